// Round 2
// baseline (1974.232 us; speedup 1.0000x reference)
//
#include <hip/hip_runtime.h>
#include <hip/hip_bf16.h>
#include <hip/hip_fp16.h>
#include <stdint.h>

#define D_  256   // emb dim
#define FD_ 512   // feat dim
#define L_  5     // layers
#define EPS_ 1e-5f

// packed-tile format (R6-proven): tile = 128 rows x 32 k, stored as 4 k-planes
// (8 k each): plane = 128 rows x 16B + 64B pad = 2112B. tile = 8448B = 4224 sh.
#define PLANE_SH 1056
#define TILE_SH  4224

typedef unsigned short ushort_t;
typedef __attribute__((ext_vector_type(8))) _Float16 h8v;  // 8 f16 (MFMA frag)
typedef __attribute__((ext_vector_type(4))) float    f4v;  // MFMA C/D frag

// numerically-stable softplus == jnp.logaddexp(x, 0) — NATIVE exp/log (R11-proven)
__device__ __forceinline__ float sp(float x) {
    float t = __expf(-fabsf(x));            // native v_exp_f32
    return fmaxf(x, 0.f) + __logf(1.f + t); // native v_log_f32
}

__device__ __forceinline__ ushort_t f2h_bits(float v) {
    union { _Float16 h; ushort_t u; } c;
    c.h = (_Float16)v;
    return c.u;
}

__device__ __forceinline__ float h2f(ushort_t u) {
    union { ushort_t u; _Float16 h; } c;
    c.u = u;
    return (float)c.h;
}

// packed-f16 element offset for (row gm, col gn) with nKB = cols/32
__device__ __forceinline__ size_t pk_off(int gm, int gn, int nKB) {
    return ((size_t)(gm >> 7) * nKB + (gn >> 5)) * TILE_SH
         + (size_t)((gn >> 3) & 3) * PLANE_SH
         + (gm & 127) * 8 + (gn & 7);
}

// ---------------------------------------------------------------------------
// h16[i,d] = f16( x_emb1[atomics[i],d] + pos[i,:] @ x_emb2_w[:,d] + x_emb2_b[d] )
// ---------------------------------------------------------------------------
__global__ __launch_bounds__(256)
void init_h_kernel(const int* __restrict__ atomics, const float* __restrict__ pos,
                   const float* __restrict__ emb1, const float* __restrict__ w2,
                   const float* __restrict__ b2, ushort_t* __restrict__ h16, int N)
{
    int i = blockIdx.x;
    int d = threadIdx.x;
    int a = atomics[i];
    float p0 = pos[(size_t)i * 3 + 0];
    float p1 = pos[(size_t)i * 3 + 1];
    float p2 = pos[(size_t)i * 3 + 2];
    float v = emb1[(size_t)a * D_ + d]
            + p0 * w2[0 * D_ + d]
            + p1 * w2[1 * D_ + d]
            + p2 * w2[2 * D_ + d]
            + b2[d];
    h16[(size_t)i * D_ + d] = f2h_bits(v);
}

// ---------------------------------------------------------------------------
// CSR build (unordered segments; segment order irrelevant)
// ---------------------------------------------------------------------------
__global__ __launch_bounds__(256)
void hist_kernel(const int* __restrict__ dst, int* __restrict__ cnt, int E)
{
    int e = blockIdx.x * 256 + threadIdx.x;
    if (e < E) atomicAdd(&cnt[dst[e]], 1);
}

__global__ __launch_bounds__(256)
void alloc_kernel(const int* __restrict__ cnt, int* __restrict__ start,
                  int* __restrict__ cursor, int* __restrict__ total, int N)
{
    int i = blockIdx.x * 256 + threadIdx.x;
    if (i < N) {
        int s = atomicAdd(total, cnt[i]);
        start[i] = s;
        cursor[i] = s;
    }
}

__global__ __launch_bounds__(256)
void fill_kernel(const int* __restrict__ src, const int* __restrict__ dst,
                 const int* __restrict__ attr, int* __restrict__ cursor,
                 uint32_t* __restrict__ elist, int E)
{
    int e = blockIdx.x * 256 + threadIdx.x;
    if (e < E) {
        int p = atomicAdd(&cursor[dst[e]], 1);
        elist[p] = (uint32_t)src[e] | ((uint32_t)attr[e] << 30);
    }
}

// ---------------------------------------------------------------------------
// act16 (R15-proven): hact = f16( sp( BN-affine(h16) ) ), 8 ch/thread
// ---------------------------------------------------------------------------
__global__ __launch_bounds__(256)
void act16_kernel(const ushort_t* __restrict__ h16, ushort_t* __restrict__ hact,
                  const float* __restrict__ bnsum, const float* __restrict__ gamma,
                  const float* __restrict__ beta, long long total8, float invN)
{
    __shared__ float ssc[256], ssh[256];
    int t = threadIdx.x;
    {
        float mean = bnsum[t] * invN;
        float var = bnsum[D_ + t] * invN - mean * mean;
        float sc = gamma[t] * rsqrtf(fmaxf(var, 0.f) + EPS_);
        ssc[t] = sc;
        ssh[t] = beta[t] - mean * sc;
    }
    __syncthreads();
    long long idx = (long long)blockIdx.x * 256 + t;
    if (idx >= total8) return;
    int c0 = (int)((idx * 8) & 255);
    uint4 in = *(const uint4*)(h16 + idx * 8);
    ushort_t* ip = (ushort_t*)&in;
    ushort_t ov[8];
#pragma unroll
    for (int j = 0; j < 8; ++j)
        ov[j] = f2h_bits(sp(h2f(ip[j]) * ssc[c0 + j] + ssh[c0 + j]));
    *(uint4*)(hact + idx * 8) = *(uint4*)ov;
}

// ---------------------------------------------------------------------------
// gather_pack4 (R15-proven): 4 rows per block, pure sum, full-line packed writes
// ---------------------------------------------------------------------------
__global__ __launch_bounds__(256)
void gather_pack4_kernel(const ushort_t* __restrict__ hact, const uint32_t* __restrict__ elist,
                         const int* __restrict__ start, const int* __restrict__ cnt,
                         const float* __restrict__ ee_l, ushort_t* __restrict__ aggP, int N)
{
    int i0 = blockIdx.x * 4;
    int d = threadIdx.x;
    float ee0 = ee_l[d];        // bond 0
    float ee1 = ee_l[D_ + d];   // bond 1 (also self-loop)
    float acc[4];
#pragma unroll
    for (int r = 0; r < 4; ++r) {
        int i = i0 + r;
        if (i >= N) { acc[r] = 0.f; continue; }
        float a = h2f(hact[(size_t)i * D_ + d]) + ee1;
        int base = start[i], deg = cnt[i];
        for (int j = 0; j < deg; ++j) {
            uint32_t p = elist[base + j];
            int s = p & 0x3FFFFFFF;
            a += h2f(hact[(size_t)s * D_ + d]) + ((p >> 30) ? ee1 : ee0);
        }
        acc[r] = a;
    }
#pragma unroll
    for (int r = 0; r < 4; ++r) {
        int i = i0 + r;
        if (i < N) aggP[pk_off(i, d, 8)] = f2h_bits(acc[r]);
    }
}

// bn_pack: BN affine (no softplus) of last layer -> packed f16 (feeds feat gemm)
__global__ __launch_bounds__(256)
void bn_pack_kernel(const ushort_t* __restrict__ h16, const float* __restrict__ bnsum,
                    const float* __restrict__ gamma, const float* __restrict__ beta,
                    ushort_t* __restrict__ outP, int N, float invN)
{
    int i = blockIdx.x;
    int d = threadIdx.x;
    float mean = bnsum[d] * invN;
    float var = bnsum[D_ + d] * invN - mean * mean;
    float inv = 1.f / sqrtf(fmaxf(var, 0.f) + EPS_);
    float v = (h2f(h16[(size_t)i * D_ + d]) - mean) * inv * gamma[d] + beta[d];
    outP[pk_off(i, d, 8)] = f2h_bits(v);
}

// ---------------------------------------------------------------------------
// weight pack (R16): W fp32 [K][N] -> SINGLE f16 tiles (nb, kb), row = col n
// ---------------------------------------------------------------------------
__global__ __launch_bounds__(256)
void convert_w_pack(const float* __restrict__ W, ushort_t* __restrict__ dh,
                    int N, int nKB)
{
    int kb = blockIdx.x, nb = blockIdx.y;
    int n = threadIdx.x >> 1, half = threadIdx.x & 1;
#pragma unroll
    for (int j = 0; j < 2; ++j) {
        int kq = half * 2 + j;
        size_t o = (size_t)(nb * nKB + kb) * TILE_SH + kq * PLANE_SH + n * 8;
#pragma unroll
        for (int jj = 0; jj < 8; ++jj) {
            float w = W[(size_t)(kb * 32 + kq * 8 + jj) * N + nb * 128 + n];
            dh[o + jj] = f2h_bits(w);
        }
    }
}

// ---------------------------------------------------------------------------
// gemm_p16<EPI> [R19]: BARRIER-FREE direct-load GEMM. The packed-tile format
// makes every MFMA fragment a contiguous 16B global line, so each wave loads
// its A/B frags straight into VGPRs (global_load_dwordx4), no LDS, no
// __syncthreads. Waves are fully independent -> no convoying; the compiler
// emits natural counted vmcnt for the register ping-pong (F/G, static names).
// Per K-step: 8 x 16B loads + 16 MFMA under setprio(1) (independent-wave
// regime = T5's proven case). Occupancy: LDS=0, VGPR-capped 3 waves/SIMD.
//   EPI 0: softplus -> packed f16 Tout (nKBo = N/32), hoisted affine addr
//   EPI 1: f16 row-major Tout[m][N] (raw h) + fused bn partial sums (N == 256)
//   EPI 2: run-merged atomicAdd into Cout[batch[gm]*N + gn]  (graph pool)
// 1-D grid ceil(mb/8)*8*NB (XCD swizzle); block 256 thr / 4 waves; tile
// 128x128 per block = 64x64 per wave.  nKB is always even (8 or 16).
// ---------------------------------------------------------------------------
template <int EPI>
__global__ __launch_bounds__(256, 3)
void gemm_p16(const ushort_t* __restrict__ APK, const ushort_t* __restrict__ BPK,
              const float* __restrict__ bias,
              ushort_t* __restrict__ Tout, float* __restrict__ Cout,
              float* __restrict__ bnsum, const int* __restrict__ batch,
              int m, int N, int nKB)
{
    const int NB = N >> 7;
    const int mb = (m + 127) >> 7;
    int id = blockIdx.x;
    int grp = id / (8 * NB);
    int rem = id - grp * 8 * NB;
    int nb = rem >> 3;
    int rb = grp * 8 + (rem & 7);
    if (rb >= mb) return;   // uniform early-out (tail row-group)

    int tid = threadIdx.x, wave = tid >> 6, lane = tid & 63;
    int wr = wave >> 1, wc = wave & 1;
    int fr = lane & 15, kq = lane >> 4;

    // per-lane fragment base: frag t of K-block kb lives at + kb*TILE_SH + t*128
    const ushort_t* aP = APK + (size_t)rb * nKB * TILE_SH
                       + (size_t)kq * PLANE_SH + (size_t)(wr * 64 + fr) * 8;
    const ushort_t* bP = BPK + (size_t)nb * nKB * TILE_SH
                       + (size_t)kq * PLANE_SH + (size_t)(wc * 64 + fr) * 8;

    f4v acc[4][4];
#pragma unroll
    for (int i = 0; i < 4; ++i)
#pragma unroll
        for (int j = 0; j < 4; ++j)
            acc[i][j] = (f4v){0.f, 0.f, 0.f, 0.f};

    h8v Fa[4], Fb[4], Ga[4], Gb[4];

#define LOADF(dA, dB, kbi)                                                   \
    {   const ushort_t* ap_ = aP + (size_t)(kbi) * TILE_SH;                  \
        const ushort_t* bp_ = bP + (size_t)(kbi) * TILE_SH;                  \
        _Pragma("unroll")                                                    \
        for (int t = 0; t < 4; ++t) {                                        \
            dA[t] = *(const h8v*)(ap_ + t * 128);                            \
            dB[t] = *(const h8v*)(bp_ + t * 128);                            \
        } }

#define MFMA16(sA, sB)                                                       \
    {   __builtin_amdgcn_s_setprio(1);                                       \
        _Pragma("unroll")                                                    \
        for (int rt = 0; rt < 4; ++rt)                                       \
            _Pragma("unroll")                                                \
            for (int ct = 0; ct < 4; ++ct)                                   \
                acc[rt][ct] = __builtin_amdgcn_mfma_f32_16x16x32_f16(        \
                    sA[rt], sB[ct], acc[rt][ct], 0, 0, 0);                   \
        __builtin_amdgcn_s_setprio(0); }

    LOADF(Fa, Fb, 0);
    for (int kb = 0; kb < nKB; kb += 2) {
        LOADF(Ga, Gb, kb + 1);              // nKB even -> kb+1 always valid
        MFMA16(Fa, Fb);                     // waits only F's 8 loads (G in flight)
        if (kb + 2 < nKB) LOADF(Fa, Fb, kb + 2);
        MFMA16(Ga, Gb);
    }
#undef LOADF
#undef MFMA16

    // epilogue: C/D layout col = lane&15, row = (lane>>4)*4 + reg
    int gm00 = rb * 128 + wr * 64 + kq * 4;
    int gn0  = nb * 128 + wc * 64 + fr;
    int nKBo = N >> 5;
    // hoisted packed-out addressing (EPI 0): all outputs live in row-tile rb,
    // col-tiles nb*4 + wc*2 + (ct>>1); plane = (2*ct + fr>>3)&3; col = fr&7
    size_t tileRow = (size_t)(rb * nKBo + nb * 4 + wc * 2) * TILE_SH
                   + (size_t)((wr * 64 + kq * 4) * 8 + (fr & 7));
#pragma unroll
    for (int ct = 0; ct < 4; ++ct) {
        int gn = gn0 + ct * 16;
        float bv = bias[gn];
        float s = 0.f, ss = 0.f;
        size_t cb = tileRow + (size_t)(ct >> 1) * TILE_SH
                  + (size_t)((2 * ct + (fr >> 3)) & 3) * PLANE_SH;
#pragma unroll
        for (int rt = 0; rt < 4; ++rt) {
            if (EPI == 2) {
                int bp = -1; float run = 0.f;
#pragma unroll
                for (int rr = 0; rr < 4; ++rr) {
                    int gm = gm00 + rt * 16 + rr;
                    if (gm >= m) continue;
                    float v = acc[rt][ct][rr] + bv;
                    int bg = batch[gm];
                    if (bg == bp) { run += v; }
                    else {
                        if (bp >= 0) atomicAdd(&Cout[(size_t)bp * N + gn], run);
                        bp = bg; run = v;
                    }
                }
                if (bp >= 0) atomicAdd(&Cout[(size_t)bp * N + gn], run);
            } else {
#pragma unroll
                for (int rr = 0; rr < 4; ++rr) {
                    int gm = gm00 + rt * 16 + rr;
                    if (gm >= m) continue;
                    float v = acc[rt][ct][rr] + bv;
                    if (EPI == 0) {
                        Tout[cb + (rt * 16 + rr) * 8] = f2h_bits(sp(v));
                    } else {
                        Tout[(size_t)gm * N + gn] = f2h_bits(v);  // raw h, f16
                        s += v;
                        ss += v * v;
                    }
                }
            }
        }
        if (EPI == 1) {
            s  += __shfl_xor(s, 16);  s  += __shfl_xor(s, 32);
            ss += __shfl_xor(ss, 16); ss += __shfl_xor(ss, 32);
            if (kq == 0) {
                atomicAdd(&bnsum[gn], s);
                atomicAdd(&bnsum[D_ + gn], ss);
            }
        }
    }
}

// ---------------------------------------------------------------------------
__global__ __launch_bounds__(256)
void count_kernel(const int* __restrict__ batch, float* __restrict__ cnt, int N)
{
    int i = blockIdx.x * 256 + threadIdx.x;
    if (i < N) atomicAdd(&cnt[batch[i]], 1.f);
}

__global__ __launch_bounds__(256)
void pool_div_kernel(float* __restrict__ gfeat, const float* __restrict__ cnt, int G)
{
    int g = blockIdx.x;
    float inv = 1.f / fmaxf(cnt[g], 1.f);
    for (int c = threadIdx.x; c < FD_; c += 256)
        gfeat[(size_t)g * FD_ + c] *= inv;
}

// ---------------------------------------------------------------------------
// fp32 GEMM for the small head: C = softplus(A @ W + bias)
// ---------------------------------------------------------------------------
#define BM 64
#define BN 64
#define BK 16

__global__ __launch_bounds__(256)
void gemm_head(const float* __restrict__ A, const float* __restrict__ W,
               const float* __restrict__ bias, float* __restrict__ C,
               int M, int N, int K)
{
    __shared__ float As[BK][BM + 4];
    __shared__ float Ws[BK][BN + 4];

    int tid = threadIdx.x;
    int bm = blockIdx.y * BM;
    int bn = blockIdx.x * BN;
    int tx = tid & 15;
    int ty = tid >> 4;

    float acc[4][4] = {};

    int a_m = tid >> 2;
    int a_k = (tid & 3) * 4;
    int w_k = tid >> 4;
    int w_n = (tid & 15) * 4;

    for (int k0 = 0; k0 < K; k0 += BK) {
        int gm = bm + a_m;
        float4 av = make_float4(0.f, 0.f, 0.f, 0.f);
        if (gm < M)
            av = *(const float4*)(A + (size_t)gm * K + k0 + a_k);
        As[a_k + 0][a_m] = av.x;
        As[a_k + 1][a_m] = av.y;
        As[a_k + 2][a_m] = av.z;
        As[a_k + 3][a_m] = av.w;

        float4 wv = *(const float4*)(W + (size_t)(k0 + w_k) * N + bn + w_n);
        *(float4*)&Ws[w_k][w_n] = wv;

        __syncthreads();

#pragma unroll
        for (int k = 0; k < BK; ++k) {
            float4 a4 = *(const float4*)&As[k][ty * 4];
            float4 b4 = *(const float4*)&Ws[k][tx * 4];
            float a[4] = {a4.x, a4.y, a4.z, a4.w};
            float b[4] = {b4.x, b4.y, b4.z, b4.w};
#pragma unroll
            for (int i = 0; i < 4; ++i)
#pragma unroll
                for (int j = 0; j < 4; ++j)
                    acc[i][j] += a[i] * b[j];
        }
        __syncthreads();
    }

#pragma unroll
    for (int i = 0; i < 4; ++i) {
        int gm = bm + ty * 4 + i;
        if (gm >= M) continue;
#pragma unroll
        for (int j = 0; j < 4; ++j) {
            int gn = bn + tx * 4 + j;
            C[(size_t)gm * N + gn] = sp(acc[i][j] + bias[gn]);
        }
    }
}

__global__ __launch_bounds__(256)
void head2_kernel(const float* __restrict__ hid, const float* __restrict__ w2,
                  const float* __restrict__ b2, float* __restrict__ out, int G)
{
    __shared__ float red[256];
    int g = blockIdx.x;
    int t = threadIdx.x;
    float v = hid[(size_t)g * 256 + t] * w2[t];
    red[t] = v;
    __syncthreads();
    for (int s = 128; s > 0; s >>= 1) {
        if (t < s) red[t] += red[t + s];
        __syncthreads();
    }
    if (t == 0) out[g] = red[0] + b2[0];
}

// ---------------------------------------------------------------------------
extern "C" void kernel_launch(void* const* d_in, const int* in_sizes, int n_in,
                              void* d_out, int out_size, void* d_ws, size_t ws_size,
                              hipStream_t stream)
{
    const int N = in_sizes[0];
    const int E = in_sizes[3];
    const int G = out_size;

    const int*   atomics  = (const int*)d_in[0];
    const float* pos      = (const float*)d_in[1];
    const int*   eidx     = (const int*)d_in[2];
    const int*   eattr    = (const int*)d_in[3];
    const int*   batch    = (const int*)d_in[4];
    const float* x_emb1   = (const float*)d_in[5];
    const float* x_emb2_w = (const float*)d_in[6];
    const float* x_emb2_b = (const float*)d_in[7];
    const float* edge_emb = (const float*)d_in[8];
    const float* mlp_w1   = (const float*)d_in[9];
    const float* mlp_b1   = (const float*)d_in[10];
    const float* mlp_w2   = (const float*)d_in[11];
    const float* mlp_b2   = (const float*)d_in[12];
    const float* bn_g     = (const float*)d_in[13];
    const float* bn_b     = (const float*)d_in[14];
    const float* feat_w   = (const float*)d_in[15];
    const float* feat_b   = (const float*)d_in[16];
    const float* head_w1  = (const float*)d_in[17];
    const float* head_b1  = (const float*)d_in[18];
    const float* head_w2  = (const float*)d_in[19];
    const float* head_b2  = (const float*)d_in[20];
    float* out = (float*)d_out;

    const int* src = eidx;
    const int* dst = eidx + E;

    char* ws = (char*)d_ws;
    size_t off = 0;
    auto carve = [&](size_t bytes) {
        void* p = ws + off;
        off += (bytes + 255) & ~(size_t)255;
        return p;
    };

    const int nRB = (N + 127) / 128;           // 128-row tiles

    // ---- fixed carve (~175 MB) ----
    ushort_t* h16  = (ushort_t*)carve((size_t)N * D_ * 2);             // 51.2 MB
    ushort_t* hact = (ushort_t*)carve((size_t)N * D_ * 2);             // 51.2 MB
    ushort_t* aggP = (ushort_t*)carve((size_t)nRB * 8 * TILE_SH * 2);  // 52.9 MB
    const size_t WTILES = 32 * TILE_SH;
    ushort_t* w1P = (ushort_t*)carve((size_t)L_ * WTILES * 2);
    ushort_t* w2P = (ushort_t*)carve((size_t)L_ * WTILES * 2);
    ushort_t* fP  = (ushort_t*)carve(WTILES * 2);
    float* bnsum  = (float*)carve(2 * D_ * 4);
    float* gfeat  = (float*)carve((size_t)G * FD_ * 4);                // 8.2 MB
    float* cnt    = (float*)carve((size_t)G * 4);
    float* hid    = (float*)carve((size_t)G * (FD_ / 2) * 4);
    // CSR buffers (~5 MB)
    int* cnt_i   = (int*)carve((size_t)N * 4);
    int* start_i = (int*)carve((size_t)N * 4);
    int* cursor  = (int*)carve((size_t)N * 4);
    int* total   = (int*)carve(4);
    uint32_t* elist = (uint32_t*)carve((size_t)E * 4);

    // ---- adaptive chunk for packed f16 T (16 tiles x 8448 B per 128 rows) ----
    size_t avail = (ws_size > off + 4096) ? (ws_size - off - 4096) : 0;
    long long mcb = (long long)(avail / (16 * (size_t)TILE_SH * 2));
    if (mcb > nRB) mcb = nRB;
    if (mcb < 16) mcb = 16;                    // floor (ws proven >= this)
    const int Mc = (int)(mcb * 128);
    ushort_t* tP = (ushort_t*)carve((size_t)mcb * 16 * TILE_SH * 2);

    const float invN = 1.f / (float)N;

    // ---- CSR build (once per launch, reused all 5 layers) ----
    hipMemsetAsync(cnt_i, 0, (size_t)N * 4, stream);
    hipMemsetAsync(total, 0, 4, stream);
    hist_kernel<<<(E + 255) / 256, 256, 0, stream>>>(dst, cnt_i, E);
    alloc_kernel<<<(N + 255) / 256, 256, 0, stream>>>(cnt_i, start_i, cursor, total, N);
    fill_kernel<<<(E + 255) / 256, 256, 0, stream>>>(src, dst, eattr, cursor, elist, E);

    // ---- one-time weight packing (single f16) ----
    for (int l = 0; l < L_; ++l) {
        convert_w_pack<<<dim3(8, 4), 256, 0, stream>>>(
            mlp_w1 + (size_t)l * D_ * FD_, w1P + (size_t)l * WTILES, FD_, 8);
        convert_w_pack<<<dim3(16, 2), 256, 0, stream>>>(
            mlp_w2 + (size_t)l * FD_ * D_, w2P + (size_t)l * WTILES, D_, 16);
    }
    convert_w_pack<<<dim3(8, 4), 256, 0, stream>>>(feat_w, fP, FD_, 8);

    init_h_kernel<<<N, 256, 0, stream>>>(atomics, pos, x_emb1, x_emb2_w, x_emb2_b, h16, N);

    const long long total8 = (long long)N * D_ / 8;
    const int ACTB = (int)((total8 + 255) / 256);
    const int GB4 = (N + 3) / 4;

    // swizzled 1-D grid sizes: ceil(mb/8)*8*NB
    auto swgrid = [](int mb, int NBc) { return ((mb + 7) / 8) * 8 * NBc; };

    for (int l = 0; l < L_; ++l) {
        const float* ee_l = edge_emb + (size_t)l * 2 * D_;
        const ushort_t* gsrc = h16;
        if (l > 0) {
            act16_kernel<<<ACTB, 256, 0, stream>>>(h16, hact, bnsum,
                bn_g + (size_t)(l - 1) * D_, bn_b + (size_t)(l - 1) * D_, total8, invN);
            gsrc = hact;
        }
        gather_pack4_kernel<<<GB4, 256, 0, stream>>>(gsrc, elist, start_i, cnt_i,
                                                     ee_l, aggP, N);

        hipMemsetAsync(bnsum, 0, 2 * D_ * 4, stream);
        for (int r0 = 0; r0 < N; r0 += Mc) {
            int m = min(Mc, N - r0);
            int mb = (m + 127) / 128;
            // T = sp(agg @ W1 + b1)  -> packed f16     [NB = 4]
            gemm_p16<0><<<swgrid(mb, 4), 256, 0, stream>>>(
                aggP + (size_t)(r0 >> 7) * 8 * TILE_SH,
                w1P + (size_t)l * WTILES,
                mlp_b1 + (size_t)l * FD_, tP, nullptr, nullptr, nullptr,
                m, FD_, 8);
            // h16 = f16(T @ W2 + b2) raw + bn stats    [NB = 2]
            gemm_p16<1><<<swgrid(mb, 2), 256, 0, stream>>>(
                tP, w2P + (size_t)l * WTILES,
                mlp_b2 + (size_t)l * D_, h16 + (size_t)r0 * D_, nullptr, bnsum, nullptr,
                m, D_, 16);
        }
    }

    // ---- feat + mean-pool: BN(h16) -> packed f16 (reuse aggP), pooled gemm ----
    bn_pack_kernel<<<N, 256, 0, stream>>>(h16, bnsum, bn_g + (size_t)(L_ - 1) * D_,
                                          bn_b + (size_t)(L_ - 1) * D_, aggP, N, invN);
    hipMemsetAsync(gfeat, 0, (size_t)G * FD_ * 4, stream);
    hipMemsetAsync(cnt, 0, (size_t)G * 4, stream);
    gemm_p16<2><<<swgrid(nRB, 4), 256, 0, stream>>>(
        aggP, fP, feat_b, nullptr, gfeat, nullptr, batch, N, FD_, 8);
    count_kernel<<<(N + 255) / 256, 256, 0, stream>>>(batch, cnt, N);
    pool_div_kernel<<<G, 256, 0, stream>>>(gfeat, cnt, G);

    // ---- head ----
    gemm_head<<<dim3((FD_ / 2) / BN, (G + BM - 1) / BM), 256, 0, stream>>>(
        gfeat, head_w1, head_b1, hid, G, FD_ / 2, FD_);
    head2_kernel<<<G, 256, 0, stream>>>(hid, head_w2, head_b2, out, G);
}

// Round 3
// 1496.927 us; speedup vs baseline: 1.3189x; 1.3189x over previous
//
#include <hip/hip_runtime.h>
#include <hip/hip_bf16.h>
#include <hip/hip_fp16.h>
#include <stdint.h>

#define D_  256   // emb dim
#define FD_ 512   // feat dim
#define L_  5     // layers
#define EPS_ 1e-5f

// packed-tile format (R6-proven): tile = 128 rows x 32 k, stored as 4 k-planes
// (8 k each): plane = 128 rows x 16B + 64B pad = 2112B. tile = 8448B = 4224 sh.
#define PLANE_SH 1056
#define TILE_SH  4224

typedef unsigned short ushort_t;
typedef __attribute__((ext_vector_type(8))) _Float16 h8v;  // 8 f16 (MFMA frag)
typedef __attribute__((ext_vector_type(4))) float    f4v;  // MFMA C/D frag

// numerically-stable softplus == jnp.logaddexp(x, 0) — NATIVE exp/log (R11-proven)
__device__ __forceinline__ float sp(float x) {
    float t = __expf(-fabsf(x));            // native v_exp_f32
    return fmaxf(x, 0.f) + __logf(1.f + t); // native v_log_f32
}

__device__ __forceinline__ ushort_t f2h_bits(float v) {
    union { _Float16 h; ushort_t u; } c;
    c.h = (_Float16)v;
    return c.u;
}

__device__ __forceinline__ float h2f(ushort_t u) {
    union { ushort_t u; _Float16 h; } c;
    c.u = u;
    return (float)c.h;
}

// packed-f16 element offset for (row gm, col gn) with nKB = cols/32
__device__ __forceinline__ size_t pk_off(int gm, int gn, int nKB) {
    return ((size_t)(gm >> 7) * nKB + (gn >> 5)) * TILE_SH
         + (size_t)((gn >> 3) & 3) * PLANE_SH
         + (gm & 127) * 8 + (gn & 7);
}

// ---------------------------------------------------------------------------
// h16[i,d] = f16( x_emb1[atomics[i],d] + pos[i,:] @ x_emb2_w[:,d] + x_emb2_b[d] )
// ---------------------------------------------------------------------------
__global__ __launch_bounds__(256)
void init_h_kernel(const int* __restrict__ atomics, const float* __restrict__ pos,
                   const float* __restrict__ emb1, const float* __restrict__ w2,
                   const float* __restrict__ b2, ushort_t* __restrict__ h16, int N)
{
    int i = blockIdx.x;
    int d = threadIdx.x;
    int a = atomics[i];
    float p0 = pos[(size_t)i * 3 + 0];
    float p1 = pos[(size_t)i * 3 + 1];
    float p2 = pos[(size_t)i * 3 + 2];
    float v = emb1[(size_t)a * D_ + d]
            + p0 * w2[0 * D_ + d]
            + p1 * w2[1 * D_ + d]
            + p2 * w2[2 * D_ + d]
            + b2[d];
    h16[(size_t)i * D_ + d] = f2h_bits(v);
}

// ---------------------------------------------------------------------------
// CSR build (unordered segments; segment order irrelevant)
// ---------------------------------------------------------------------------
__global__ __launch_bounds__(256)
void hist_kernel(const int* __restrict__ dst, int* __restrict__ cnt, int E)
{
    int e = blockIdx.x * 256 + threadIdx.x;
    if (e < E) atomicAdd(&cnt[dst[e]], 1);
}

__global__ __launch_bounds__(256)
void alloc_kernel(const int* __restrict__ cnt, int* __restrict__ start,
                  int* __restrict__ cursor, int* __restrict__ total, int N)
{
    int i = blockIdx.x * 256 + threadIdx.x;
    if (i < N) {
        int s = atomicAdd(total, cnt[i]);
        start[i] = s;
        cursor[i] = s;
    }
}

__global__ __launch_bounds__(256)
void fill_kernel(const int* __restrict__ src, const int* __restrict__ dst,
                 const int* __restrict__ attr, int* __restrict__ cursor,
                 uint32_t* __restrict__ elist, int E)
{
    int e = blockIdx.x * 256 + threadIdx.x;
    if (e < E) {
        int p = atomicAdd(&cursor[dst[e]], 1);
        elist[p] = (uint32_t)src[e] | ((uint32_t)attr[e] << 30);
    }
}

// ---------------------------------------------------------------------------
// act16 (R15-proven): hact = f16( sp( BN-affine(h16) ) ), 8 ch/thread
// ---------------------------------------------------------------------------
__global__ __launch_bounds__(256)
void act16_kernel(const ushort_t* __restrict__ h16, ushort_t* __restrict__ hact,
                  const float* __restrict__ bnsum, const float* __restrict__ gamma,
                  const float* __restrict__ beta, long long total8, float invN)
{
    __shared__ float ssc[256], ssh[256];
    int t = threadIdx.x;
    {
        float mean = bnsum[t] * invN;
        float var = bnsum[D_ + t] * invN - mean * mean;
        float sc = gamma[t] * rsqrtf(fmaxf(var, 0.f) + EPS_);
        ssc[t] = sc;
        ssh[t] = beta[t] - mean * sc;
    }
    __syncthreads();
    long long idx = (long long)blockIdx.x * 256 + t;
    if (idx >= total8) return;
    int c0 = (int)((idx * 8) & 255);
    uint4 in = *(const uint4*)(h16 + idx * 8);
    ushort_t* ip = (ushort_t*)&in;
    ushort_t ov[8];
#pragma unroll
    for (int j = 0; j < 8; ++j)
        ov[j] = f2h_bits(sp(h2f(ip[j]) * ssc[c0 + j] + ssh[c0 + j]));
    *(uint4*)(hact + idx * 8) = *(uint4*)ov;
}

// ---------------------------------------------------------------------------
// gather_pack4 (R15-proven): 4 rows per block, pure sum, full-line packed writes
// ---------------------------------------------------------------------------
__global__ __launch_bounds__(256)
void gather_pack4_kernel(const ushort_t* __restrict__ hact, const uint32_t* __restrict__ elist,
                         const int* __restrict__ start, const int* __restrict__ cnt,
                         const float* __restrict__ ee_l, ushort_t* __restrict__ aggP, int N)
{
    int i0 = blockIdx.x * 4;
    int d = threadIdx.x;
    float ee0 = ee_l[d];        // bond 0
    float ee1 = ee_l[D_ + d];   // bond 1 (also self-loop)
    float acc[4];
#pragma unroll
    for (int r = 0; r < 4; ++r) {
        int i = i0 + r;
        if (i >= N) { acc[r] = 0.f; continue; }
        float a = h2f(hact[(size_t)i * D_ + d]) + ee1;
        int base = start[i], deg = cnt[i];
        for (int j = 0; j < deg; ++j) {
            uint32_t p = elist[base + j];
            int s = p & 0x3FFFFFFF;
            a += h2f(hact[(size_t)s * D_ + d]) + ((p >> 30) ? ee1 : ee0);
        }
        acc[r] = a;
    }
#pragma unroll
    for (int r = 0; r < 4; ++r) {
        int i = i0 + r;
        if (i < N) aggP[pk_off(i, d, 8)] = f2h_bits(acc[r]);
    }
}

// bn_pack: BN affine (no softplus) of last layer -> packed f16 (feeds feat gemm)
__global__ __launch_bounds__(256)
void bn_pack_kernel(const ushort_t* __restrict__ h16, const float* __restrict__ bnsum,
                    const float* __restrict__ gamma, const float* __restrict__ beta,
                    ushort_t* __restrict__ outP, int N, float invN)
{
    int i = blockIdx.x;
    int d = threadIdx.x;
    float mean = bnsum[d] * invN;
    float var = bnsum[D_ + d] * invN - mean * mean;
    float inv = 1.f / sqrtf(fmaxf(var, 0.f) + EPS_);
    float v = (h2f(h16[(size_t)i * D_ + d]) - mean) * inv * gamma[d] + beta[d];
    outP[pk_off(i, d, 8)] = f2h_bits(v);
}

// ---------------------------------------------------------------------------
// weight pack (R16): W fp32 [K][N] -> SINGLE f16 tiles (nb, kb), row = col n
// ---------------------------------------------------------------------------
__global__ __launch_bounds__(256)
void convert_w_pack(const float* __restrict__ W, ushort_t* __restrict__ dh,
                    int N, int nKB)
{
    int kb = blockIdx.x, nb = blockIdx.y;
    int n = threadIdx.x >> 1, half = threadIdx.x & 1;
#pragma unroll
    for (int j = 0; j < 2; ++j) {
        int kq = half * 2 + j;
        size_t o = (size_t)(nb * nKB + kb) * TILE_SH + kq * PLANE_SH + n * 8;
#pragma unroll
        for (int jj = 0; jj < 8; ++jj) {
            float w = W[(size_t)(kb * 32 + kq * 8 + jj) * N + nb * 128 + n];
            dh[o + jj] = f2h_bits(w);
        }
    }
}

// ---------------------------------------------------------------------------
// fused_mlp_kernel [R20]: BOTH layer GEMMs in one kernel. Block = 64 rows x
// 8 waves (512 thr), 2 blocks/CU (LDS 64KB, launch_bounds(512,4)).
//   stage1: T = sp(A @ W1 + b1)  (64x512) -> LDS in packed-fragment layout
//           (UNPADDED planes: tile kb2 = 2048 sh, plane = 512 sh). wave w
//           owns cols [w*64, w*64+64): per kb 4 A-frags + 4 W1-frags, 16 MFMA.
//           A-frags identical across the 8 waves -> L1 broadcast.
//   barrier (the only one)
//   stage2: h = T @ W2 + b2  (64x256). wave w owns cols [w*32, w*32+32):
//           per kb2 4 T-frags (ds_read_b128) + 2 W2-frags, 8 MFMA.
//   epilogue: h16 row-major f16 + fused bn partial sums (atomics, kq==0).
// T NEVER touches HBM (was 102MB write + 102MB read per layer).
// ---------------------------------------------------------------------------
__global__ __launch_bounds__(512, 4)
void fused_mlp_kernel(const ushort_t* __restrict__ APK,
                      const ushort_t* __restrict__ W1P,
                      const ushort_t* __restrict__ W2P,
                      const float* __restrict__ b1,
                      const float* __restrict__ b2,
                      ushort_t* __restrict__ Hout,
                      float* __restrict__ bnsum,
                      int m)
{
    __shared__ ushort_t Tl[32768];   // 64 rows x 512 cols packed f16 = 64 KB

    int rb = blockIdx.x;             // 64-row block
    int tid = threadIdx.x, w = tid >> 6, lane = tid & 63;
    int fr = lane & 15, kq = lane >> 4;

    // ---- stage 1: cols [w*64, w*64+64) ----
    const ushort_t* aT = APK + (size_t)(rb >> 1) * (8 * TILE_SH)
                       + (size_t)kq * PLANE_SH + (size_t)((rb & 1) * 64 + fr) * 8;
    const ushort_t* bT = W1P + (size_t)(w >> 1) * (8 * TILE_SH)
                       + (size_t)kq * PLANE_SH + (size_t)((w & 1) * 64 + fr) * 8;

    f4v acc1[4][4];
#pragma unroll
    for (int i = 0; i < 4; ++i)
#pragma unroll
        for (int j = 0; j < 4; ++j)
            acc1[i][j] = (f4v){0.f, 0.f, 0.f, 0.f};

    for (int kb = 0; kb < 8; ++kb) {
        h8v Af[4], Bf[4];
#pragma unroll
        for (int t = 0; t < 4; ++t) {
            Af[t] = *(const h8v*)(aT + (size_t)kb * TILE_SH + t * 128);
            Bf[t] = *(const h8v*)(bT + (size_t)kb * TILE_SH + t * 128);
        }
        __builtin_amdgcn_s_setprio(1);
#pragma unroll
        for (int rt = 0; rt < 4; ++rt)
#pragma unroll
            for (int ct = 0; ct < 4; ++ct)
                acc1[rt][ct] = __builtin_amdgcn_mfma_f32_16x16x32_f16(
                    Af[rt], Bf[ct], acc1[rt][ct], 0, 0, 0);
        __builtin_amdgcn_s_setprio(0);
    }

    // T -> LDS (packed, unpadded planes). col = w*64 + ct*16 + fr,
    // row = rt*16 + kq*4 + rr. tile = col>>5, plane = (col>>3)&3, j = col&7.
#pragma unroll
    for (int ct = 0; ct < 4; ++ct) {
        float bv = b1[w * 64 + ct * 16 + fr];
        int base = (w * 2 + (ct >> 1)) * 2048
                 + ((( fr >> 3) + ct * 2) & 3) * 512
                 + (fr & 7);
#pragma unroll
        for (int rt = 0; rt < 4; ++rt)
#pragma unroll
            for (int rr = 0; rr < 4; ++rr) {
                int row = rt * 16 + kq * 4 + rr;
                Tl[base + row * 8] = f2h_bits(sp(acc1[rt][ct][rr] + bv));
            }
    }
    __syncthreads();

    // ---- stage 2: cols [w*32, w*32+32) of 256 ----
    const ushort_t* wT = W2P + (size_t)(w >> 2) * (16 * TILE_SH)
                       + (size_t)kq * PLANE_SH + (size_t)((w & 3) * 32 + fr) * 8;

    f4v acc2[4][2];
#pragma unroll
    for (int i = 0; i < 4; ++i)
#pragma unroll
        for (int j = 0; j < 2; ++j)
            acc2[i][j] = (f4v){0.f, 0.f, 0.f, 0.f};

    for (int kb = 0; kb < 16; ++kb) {
        h8v Tf[4], Wf[2];
#pragma unroll
        for (int t = 0; t < 4; ++t)
            Tf[t] = *(const h8v*)(Tl + kb * 2048 + kq * 512 + (fr + t * 16) * 8);
#pragma unroll
        for (int t = 0; t < 2; ++t)
            Wf[t] = *(const h8v*)(wT + (size_t)kb * TILE_SH + t * 128);
        __builtin_amdgcn_s_setprio(1);
#pragma unroll
        for (int rt = 0; rt < 4; ++rt)
#pragma unroll
            for (int ct = 0; ct < 2; ++ct)
                acc2[rt][ct] = __builtin_amdgcn_mfma_f32_16x16x32_f16(
                    Tf[rt], Wf[ct], acc2[rt][ct], 0, 0, 0);
        __builtin_amdgcn_s_setprio(0);
    }

    // ---- epilogue: row-major f16 h + bn partial sums ----
    int gm0 = rb * 64 + kq * 4;
#pragma unroll
    for (int ct = 0; ct < 2; ++ct) {
        int gn = w * 32 + ct * 16 + fr;
        float bv = b2[gn];
        float s = 0.f, ss = 0.f;
#pragma unroll
        for (int rt = 0; rt < 4; ++rt)
#pragma unroll
            for (int rr = 0; rr < 4; ++rr) {
                int gm = gm0 + rt * 16 + rr;
                if (gm < m) {
                    float v = acc2[rt][ct][rr] + bv;
                    Hout[(size_t)gm * D_ + gn] = f2h_bits(v);
                    s += v;
                    ss += v * v;
                }
            }
        s  += __shfl_xor(s, 16);  s  += __shfl_xor(s, 32);
        ss += __shfl_xor(ss, 16); ss += __shfl_xor(ss, 32);
        if (kq == 0) {
            atomicAdd(&bnsum[gn], s);
            atomicAdd(&bnsum[D_ + gn], ss);
        }
    }
}

// ---------------------------------------------------------------------------
// gemm_p16<EPI> [R19 form, used only for EPI=2 graph-pool GEMM]
// ---------------------------------------------------------------------------
template <int EPI>
__global__ __launch_bounds__(256, 3)
void gemm_p16(const ushort_t* __restrict__ APK, const ushort_t* __restrict__ BPK,
              const float* __restrict__ bias,
              ushort_t* __restrict__ Tout, float* __restrict__ Cout,
              float* __restrict__ bnsum, const int* __restrict__ batch,
              int m, int N, int nKB)
{
    const int NB = N >> 7;
    const int mb = (m + 127) >> 7;
    int id = blockIdx.x;
    int grp = id / (8 * NB);
    int rem = id - grp * 8 * NB;
    int nb = rem >> 3;
    int rb = grp * 8 + (rem & 7);
    if (rb >= mb) return;   // uniform early-out (tail row-group)

    int tid = threadIdx.x, wave = tid >> 6, lane = tid & 63;
    int wr = wave >> 1, wc = wave & 1;
    int fr = lane & 15, kq = lane >> 4;

    const ushort_t* aP = APK + (size_t)rb * nKB * TILE_SH
                       + (size_t)kq * PLANE_SH + (size_t)(wr * 64 + fr) * 8;
    const ushort_t* bP = BPK + (size_t)nb * nKB * TILE_SH
                       + (size_t)kq * PLANE_SH + (size_t)(wc * 64 + fr) * 8;

    f4v acc[4][4];
#pragma unroll
    for (int i = 0; i < 4; ++i)
#pragma unroll
        for (int j = 0; j < 4; ++j)
            acc[i][j] = (f4v){0.f, 0.f, 0.f, 0.f};

    h8v Fa[4], Fb[4], Ga[4], Gb[4];

#define LOADF(dA, dB, kbi)                                                   \
    {   const ushort_t* ap_ = aP + (size_t)(kbi) * TILE_SH;                  \
        const ushort_t* bp_ = bP + (size_t)(kbi) * TILE_SH;                  \
        _Pragma("unroll")                                                    \
        for (int t = 0; t < 4; ++t) {                                        \
            dA[t] = *(const h8v*)(ap_ + t * 128);                            \
            dB[t] = *(const h8v*)(bp_ + t * 128);                            \
        } }

#define MFMA16(sA, sB)                                                       \
    {   __builtin_amdgcn_s_setprio(1);                                       \
        _Pragma("unroll")                                                    \
        for (int rt = 0; rt < 4; ++rt)                                       \
            _Pragma("unroll")                                                \
            for (int ct = 0; ct < 4; ++ct)                                   \
                acc[rt][ct] = __builtin_amdgcn_mfma_f32_16x16x32_f16(        \
                    sA[rt], sB[ct], acc[rt][ct], 0, 0, 0);                   \
        __builtin_amdgcn_s_setprio(0); }

    LOADF(Fa, Fb, 0);
    for (int kb = 0; kb < nKB; kb += 2) {
        LOADF(Ga, Gb, kb + 1);
        MFMA16(Fa, Fb);
        if (kb + 2 < nKB) LOADF(Fa, Fb, kb + 2);
        MFMA16(Ga, Gb);
    }
#undef LOADF
#undef MFMA16

    int gm00 = rb * 128 + wr * 64 + kq * 4;
    int gn0  = nb * 128 + wc * 64 + fr;
    int nKBo = N >> 5;
    size_t tileRow = (size_t)(rb * nKBo + nb * 4 + wc * 2) * TILE_SH
                   + (size_t)((wr * 64 + kq * 4) * 8 + (fr & 7));
#pragma unroll
    for (int ct = 0; ct < 4; ++ct) {
        int gn = gn0 + ct * 16;
        float bv = bias[gn];
        float s = 0.f, ss = 0.f;
        size_t cb = tileRow + (size_t)(ct >> 1) * TILE_SH
                  + (size_t)((2 * ct + (fr >> 3)) & 3) * PLANE_SH;
#pragma unroll
        for (int rt = 0; rt < 4; ++rt) {
            if (EPI == 2) {
                int bp = -1; float run = 0.f;
#pragma unroll
                for (int rr = 0; rr < 4; ++rr) {
                    int gm = gm00 + rt * 16 + rr;
                    if (gm >= m) continue;
                    float v = acc[rt][ct][rr] + bv;
                    int bg = batch[gm];
                    if (bg == bp) { run += v; }
                    else {
                        if (bp >= 0) atomicAdd(&Cout[(size_t)bp * N + gn], run);
                        bp = bg; run = v;
                    }
                }
                if (bp >= 0) atomicAdd(&Cout[(size_t)bp * N + gn], run);
            } else {
#pragma unroll
                for (int rr = 0; rr < 4; ++rr) {
                    int gm = gm00 + rt * 16 + rr;
                    if (gm >= m) continue;
                    float v = acc[rt][ct][rr] + bv;
                    if (EPI == 0) {
                        Tout[cb + (rt * 16 + rr) * 8] = f2h_bits(sp(v));
                    } else {
                        Tout[(size_t)gm * N + gn] = f2h_bits(v);
                        s += v;
                        ss += v * v;
                    }
                }
            }
        }
        if (EPI == 1) {
            s  += __shfl_xor(s, 16);  s  += __shfl_xor(s, 32);
            ss += __shfl_xor(ss, 16); ss += __shfl_xor(ss, 32);
            if (kq == 0) {
                atomicAdd(&bnsum[gn], s);
                atomicAdd(&bnsum[D_ + gn], ss);
            }
        }
    }
}

// ---------------------------------------------------------------------------
__global__ __launch_bounds__(256)
void count_kernel(const int* __restrict__ batch, float* __restrict__ cnt, int N)
{
    int i = blockIdx.x * 256 + threadIdx.x;
    if (i < N) atomicAdd(&cnt[batch[i]], 1.f);
}

__global__ __launch_bounds__(256)
void pool_div_kernel(float* __restrict__ gfeat, const float* __restrict__ cnt, int G)
{
    int g = blockIdx.x;
    float inv = 1.f / fmaxf(cnt[g], 1.f);
    for (int c = threadIdx.x; c < FD_; c += 256)
        gfeat[(size_t)g * FD_ + c] *= inv;
}

// ---------------------------------------------------------------------------
// fp32 GEMM for the small head: C = softplus(A @ W + bias)
// ---------------------------------------------------------------------------
#define BM 64
#define BN 64
#define BK 16

__global__ __launch_bounds__(256)
void gemm_head(const float* __restrict__ A, const float* __restrict__ W,
               const float* __restrict__ bias, float* __restrict__ C,
               int M, int N, int K)
{
    __shared__ float As[BK][BM + 4];
    __shared__ float Ws[BK][BN + 4];

    int tid = threadIdx.x;
    int bm = blockIdx.y * BM;
    int bn = blockIdx.x * BN;
    int tx = tid & 15;
    int ty = tid >> 4;

    float acc[4][4] = {};

    int a_m = tid >> 2;
    int a_k = (tid & 3) * 4;
    int w_k = tid >> 4;
    int w_n = (tid & 15) * 4;

    for (int k0 = 0; k0 < K; k0 += BK) {
        int gm = bm + a_m;
        float4 av = make_float4(0.f, 0.f, 0.f, 0.f);
        if (gm < M)
            av = *(const float4*)(A + (size_t)gm * K + k0 + a_k);
        As[a_k + 0][a_m] = av.x;
        As[a_k + 1][a_m] = av.y;
        As[a_k + 2][a_m] = av.z;
        As[a_k + 3][a_m] = av.w;

        float4 wv = *(const float4*)(W + (size_t)(k0 + w_k) * N + bn + w_n);
        *(float4*)&Ws[w_k][w_n] = wv;

        __syncthreads();

#pragma unroll
        for (int k = 0; k < BK; ++k) {
            float4 a4 = *(const float4*)&As[k][ty * 4];
            float4 b4 = *(const float4*)&Ws[k][tx * 4];
            float a[4] = {a4.x, a4.y, a4.z, a4.w};
            float b[4] = {b4.x, b4.y, b4.z, b4.w};
#pragma unroll
            for (int i = 0; i < 4; ++i)
#pragma unroll
                for (int j = 0; j < 4; ++j)
                    acc[i][j] += a[i] * b[j];
        }
        __syncthreads();
    }

#pragma unroll
    for (int i = 0; i < 4; ++i) {
        int gm = bm + ty * 4 + i;
        if (gm >= M) continue;
#pragma unroll
        for (int j = 0; j < 4; ++j) {
            int gn = bn + tx * 4 + j;
            C[(size_t)gm * N + gn] = sp(acc[i][j] + bias[gn]);
        }
    }
}

__global__ __launch_bounds__(256)
void head2_kernel(const float* __restrict__ hid, const float* __restrict__ w2,
                  const float* __restrict__ b2, float* __restrict__ out, int G)
{
    __shared__ float red[256];
    int g = blockIdx.x;
    int t = threadIdx.x;
    float v = hid[(size_t)g * 256 + t] * w2[t];
    red[t] = v;
    __syncthreads();
    for (int s = 128; s > 0; s >>= 1) {
        if (t < s) red[t] += red[t + s];
        __syncthreads();
    }
    if (t == 0) out[g] = red[0] + b2[0];
}

// ---------------------------------------------------------------------------
extern "C" void kernel_launch(void* const* d_in, const int* in_sizes, int n_in,
                              void* d_out, int out_size, void* d_ws, size_t ws_size,
                              hipStream_t stream)
{
    const int N = in_sizes[0];
    const int E = in_sizes[3];
    const int G = out_size;

    const int*   atomics  = (const int*)d_in[0];
    const float* pos      = (const float*)d_in[1];
    const int*   eidx     = (const int*)d_in[2];
    const int*   eattr    = (const int*)d_in[3];
    const int*   batch    = (const int*)d_in[4];
    const float* x_emb1   = (const float*)d_in[5];
    const float* x_emb2_w = (const float*)d_in[6];
    const float* x_emb2_b = (const float*)d_in[7];
    const float* edge_emb = (const float*)d_in[8];
    const float* mlp_w1   = (const float*)d_in[9];
    const float* mlp_b1   = (const float*)d_in[10];
    const float* mlp_w2   = (const float*)d_in[11];
    const float* mlp_b2   = (const float*)d_in[12];
    const float* bn_g     = (const float*)d_in[13];
    const float* bn_b     = (const float*)d_in[14];
    const float* feat_w   = (const float*)d_in[15];
    const float* feat_b   = (const float*)d_in[16];
    const float* head_w1  = (const float*)d_in[17];
    const float* head_b1  = (const float*)d_in[18];
    const float* head_w2  = (const float*)d_in[19];
    const float* head_b2  = (const float*)d_in[20];
    float* out = (float*)d_out;

    const int* src = eidx;
    const int* dst = eidx + E;

    char* ws = (char*)d_ws;
    size_t off = 0;
    auto carve = [&](size_t bytes) {
        void* p = ws + off;
        off += (bytes + 255) & ~(size_t)255;
        return p;
    };

    const int nRB = (N + 127) / 128;           // 128-row tiles

    // ---- fixed carve (~170 MB) ----
    ushort_t* h16  = (ushort_t*)carve((size_t)N * D_ * 2);             // 51.2 MB
    ushort_t* hact = (ushort_t*)carve((size_t)N * D_ * 2);             // 51.2 MB
    ushort_t* aggP = (ushort_t*)carve((size_t)nRB * 8 * TILE_SH * 2);  // 52.9 MB
    const size_t WTILES = 32 * TILE_SH;
    ushort_t* w1P = (ushort_t*)carve((size_t)L_ * WTILES * 2);
    ushort_t* w2P = (ushort_t*)carve((size_t)L_ * WTILES * 2);
    ushort_t* fP  = (ushort_t*)carve(WTILES * 2);
    float* bnsum  = (float*)carve(2 * D_ * 4);
    float* gfeat  = (float*)carve((size_t)G * FD_ * 4);                // 8.2 MB
    float* cnt    = (float*)carve((size_t)G * 4);
    float* hid    = (float*)carve((size_t)G * (FD_ / 2) * 4);
    // CSR buffers (~5 MB)
    int* cnt_i   = (int*)carve((size_t)N * 4);
    int* start_i = (int*)carve((size_t)N * 4);
    int* cursor  = (int*)carve((size_t)N * 4);
    int* total   = (int*)carve(4);
    uint32_t* elist = (uint32_t*)carve((size_t)E * 4);

    const float invN = 1.f / (float)N;

    // ---- CSR build (once per launch, reused all 5 layers) ----
    hipMemsetAsync(cnt_i, 0, (size_t)N * 4, stream);
    hipMemsetAsync(total, 0, 4, stream);
    hist_kernel<<<(E + 255) / 256, 256, 0, stream>>>(dst, cnt_i, E);
    alloc_kernel<<<(N + 255) / 256, 256, 0, stream>>>(cnt_i, start_i, cursor, total, N);
    fill_kernel<<<(E + 255) / 256, 256, 0, stream>>>(src, dst, eattr, cursor, elist, E);

    // ---- one-time weight packing (single f16) ----
    for (int l = 0; l < L_; ++l) {
        convert_w_pack<<<dim3(8, 4), 256, 0, stream>>>(
            mlp_w1 + (size_t)l * D_ * FD_, w1P + (size_t)l * WTILES, FD_, 8);
        convert_w_pack<<<dim3(16, 2), 256, 0, stream>>>(
            mlp_w2 + (size_t)l * FD_ * D_, w2P + (size_t)l * WTILES, D_, 16);
    }
    convert_w_pack<<<dim3(8, 4), 256, 0, stream>>>(feat_w, fP, FD_, 8);

    init_h_kernel<<<N, 256, 0, stream>>>(atomics, pos, x_emb1, x_emb2_w, x_emb2_b, h16, N);

    const long long total8 = (long long)N * D_ / 8;
    const int ACTB = (int)((total8 + 255) / 256);
    const int GB4 = (N + 3) / 4;
    const int FB  = (N + 63) / 64;             // fused 64-row blocks

    for (int l = 0; l < L_; ++l) {
        const float* ee_l = edge_emb + (size_t)l * 2 * D_;
        const ushort_t* gsrc = h16;
        if (l > 0) {
            act16_kernel<<<ACTB, 256, 0, stream>>>(h16, hact, bnsum,
                bn_g + (size_t)(l - 1) * D_, bn_b + (size_t)(l - 1) * D_, total8, invN);
            gsrc = hact;
        }
        gather_pack4_kernel<<<GB4, 256, 0, stream>>>(gsrc, elist, start_i, cnt_i,
                                                     ee_l, aggP, N);

        hipMemsetAsync(bnsum, 0, 2 * D_ * 4, stream);
        fused_mlp_kernel<<<FB, 512, 0, stream>>>(
            aggP, w1P + (size_t)l * WTILES, w2P + (size_t)l * WTILES,
            mlp_b1 + (size_t)l * FD_, mlp_b2 + (size_t)l * D_,
            h16, bnsum, N);
    }

    // ---- feat + mean-pool: BN(h16) -> packed f16 (reuse aggP), pooled gemm ----
    bn_pack_kernel<<<N, 256, 0, stream>>>(h16, bnsum, bn_g + (size_t)(L_ - 1) * D_,
                                          bn_b + (size_t)(L_ - 1) * D_, aggP, N, invN);
    hipMemsetAsync(gfeat, 0, (size_t)G * FD_ * 4, stream);
    hipMemsetAsync(cnt, 0, (size_t)G * 4, stream);
    auto swgrid = [](int mb, int NBc) { return ((mb + 7) / 8) * 8 * NBc; };
    gemm_p16<2><<<swgrid(nRB, 4), 256, 0, stream>>>(
        aggP, fP, feat_b, nullptr, gfeat, nullptr, batch, N, FD_, 8);
    count_kernel<<<(N + 255) / 256, 256, 0, stream>>>(batch, cnt, N);
    pool_div_kernel<<<G, 256, 0, stream>>>(gfeat, cnt, G);

    // ---- head ----
    gemm_head<<<dim3((FD_ / 2) / BN, (G + BM - 1) / BM), 256, 0, stream>>>(
        gfeat, head_w1, head_b1, hid, G, FD_ / 2, FD_);
    head2_kernel<<<G, 256, 0, stream>>>(hid, head_w2, head_b2, out, G);
}

// Round 4
// 1273.284 us; speedup vs baseline: 1.5505x; 1.1756x over previous
//
#include <hip/hip_runtime.h>
#include <hip/hip_bf16.h>
#include <hip/hip_fp16.h>
#include <stdint.h>

#define D_  256   // emb dim
#define FD_ 512   // feat dim
#define L_  5     // layers
#define EPS_ 1e-5f

// packed-tile format (R6-proven): tile = 128 rows x 32 k, stored as 4 k-planes
// (8 k each): plane = 128 rows x 16B + 64B pad = 2112B. tile = 8448B = 4224 sh.
#define PLANE_SH 1056
#define TILE_SH  4224

typedef unsigned short ushort_t;
typedef __attribute__((ext_vector_type(8))) _Float16 h8v;  // 8 f16 (MFMA frag)
typedef __attribute__((ext_vector_type(4))) float    f4v;  // MFMA C/D frag

// numerically-stable softplus == jnp.logaddexp(x, 0) — NATIVE exp/log (R11-proven)
__device__ __forceinline__ float sp(float x) {
    float t = __expf(-fabsf(x));            // native v_exp_f32
    return fmaxf(x, 0.f) + __logf(1.f + t); // native v_log_f32
}

__device__ __forceinline__ ushort_t f2h_bits(float v) {
    union { _Float16 h; ushort_t u; } c;
    c.h = (_Float16)v;
    return c.u;
}

__device__ __forceinline__ float h2f(ushort_t u) {
    union { ushort_t u; _Float16 h; } c;
    c.u = u;
    return (float)c.h;
}

// packed-f16 element offset for (row gm, col gn) with nKB = cols/32
__device__ __forceinline__ size_t pk_off(int gm, int gn, int nKB) {
    return ((size_t)(gm >> 7) * nKB + (gn >> 5)) * TILE_SH
         + (size_t)((gn >> 3) & 3) * PLANE_SH
         + (gm & 127) * 8 + (gn & 7);
}

// ---------------------------------------------------------------------------
// h16[i,d] = f16( x_emb1[atomics[i],d] + pos[i,:] @ x_emb2_w[:,d] + x_emb2_b[d] )
// ---------------------------------------------------------------------------
__global__ __launch_bounds__(256)
void init_h_kernel(const int* __restrict__ atomics, const float* __restrict__ pos,
                   const float* __restrict__ emb1, const float* __restrict__ w2,
                   const float* __restrict__ b2, ushort_t* __restrict__ h16, int N)
{
    int i = blockIdx.x;
    int d = threadIdx.x;
    int a = atomics[i];
    float p0 = pos[(size_t)i * 3 + 0];
    float p1 = pos[(size_t)i * 3 + 1];
    float p2 = pos[(size_t)i * 3 + 2];
    float v = emb1[(size_t)a * D_ + d]
            + p0 * w2[0 * D_ + d]
            + p1 * w2[1 * D_ + d]
            + p2 * w2[2 * D_ + d]
            + b2[d];
    h16[(size_t)i * D_ + d] = f2h_bits(v);
}

// ---------------------------------------------------------------------------
// CSR build (unordered segments; segment order irrelevant)
// ---------------------------------------------------------------------------
__global__ __launch_bounds__(256)
void hist_kernel(const int* __restrict__ dst, int* __restrict__ cnt, int E)
{
    int e = blockIdx.x * 256 + threadIdx.x;
    if (e < E) atomicAdd(&cnt[dst[e]], 1);
}

__global__ __launch_bounds__(256)
void alloc_kernel(const int* __restrict__ cnt, int* __restrict__ start,
                  int* __restrict__ cursor, int* __restrict__ total, int N)
{
    int i = blockIdx.x * 256 + threadIdx.x;
    if (i < N) {
        int s = atomicAdd(total, cnt[i]);
        start[i] = s;
        cursor[i] = s;
    }
}

__global__ __launch_bounds__(256)
void fill_kernel(const int* __restrict__ src, const int* __restrict__ dst,
                 const int* __restrict__ attr, int* __restrict__ cursor,
                 uint32_t* __restrict__ elist, int E)
{
    int e = blockIdx.x * 256 + threadIdx.x;
    if (e < E) {
        int p = atomicAdd(&cursor[dst[e]], 1);
        elist[p] = (uint32_t)src[e] | ((uint32_t)attr[e] << 30);
    }
}

// ---------------------------------------------------------------------------
// graph node ranges (batch is sorted): gstart[g]..gend[g]
// ---------------------------------------------------------------------------
__global__ __launch_bounds__(256)
void range_kernel(const int* __restrict__ batch, int* __restrict__ gstart,
                  int* __restrict__ gend, int N)
{
    int i = blockIdx.x * 256 + threadIdx.x;
    if (i >= N) return;
    int b = batch[i];
    if (i == 0 || batch[i - 1] != b) gstart[b] = i;
    if (i == N - 1 || batch[i + 1] != b) gend[b] = i + 1;
}

// ---------------------------------------------------------------------------
// act16 (R15-proven): hact = f16( sp( BN-affine(h16) ) ), 8 ch/thread
// ---------------------------------------------------------------------------
__global__ __launch_bounds__(256)
void act16_kernel(const ushort_t* __restrict__ h16, ushort_t* __restrict__ hact,
                  const float* __restrict__ bnsum, const float* __restrict__ gamma,
                  const float* __restrict__ beta, long long total8, float invN)
{
    __shared__ float ssc[256], ssh[256];
    int t = threadIdx.x;
    {
        float mean = bnsum[t] * invN;
        float var = bnsum[D_ + t] * invN - mean * mean;
        float sc = gamma[t] * rsqrtf(fmaxf(var, 0.f) + EPS_);
        ssc[t] = sc;
        ssh[t] = beta[t] - mean * sc;
    }
    __syncthreads();
    long long idx = (long long)blockIdx.x * 256 + t;
    if (idx >= total8) return;
    int c0 = (int)((idx * 8) & 255);
    uint4 in = *(const uint4*)(h16 + idx * 8);
    ushort_t* ip = (ushort_t*)&in;
    ushort_t ov[8];
#pragma unroll
    for (int j = 0; j < 8; ++j)
        ov[j] = f2h_bits(sp(h2f(ip[j]) * ssc[c0 + j] + ssh[c0 + j]));
    *(uint4*)(hact + idx * 8) = *(uint4*)ov;
}

// ---------------------------------------------------------------------------
// gather_pack4 (R15-proven): 4 rows per block, pure sum, full-line packed writes
// ---------------------------------------------------------------------------
__global__ __launch_bounds__(256)
void gather_pack4_kernel(const ushort_t* __restrict__ hact, const uint32_t* __restrict__ elist,
                         const int* __restrict__ start, const int* __restrict__ cnt,
                         const float* __restrict__ ee_l, ushort_t* __restrict__ aggP, int N)
{
    int i0 = blockIdx.x * 4;
    int d = threadIdx.x;
    float ee0 = ee_l[d];        // bond 0
    float ee1 = ee_l[D_ + d];   // bond 1 (also self-loop)
    float acc[4];
#pragma unroll
    for (int r = 0; r < 4; ++r) {
        int i = i0 + r;
        if (i >= N) { acc[r] = 0.f; continue; }
        float a = h2f(hact[(size_t)i * D_ + d]) + ee1;
        int base = start[i], deg = cnt[i];
        for (int j = 0; j < deg; ++j) {
            uint32_t p = elist[base + j];
            int s = p & 0x3FFFFFFF;
            a += h2f(hact[(size_t)s * D_ + d]) + ((p >> 30) ? ee1 : ee0);
        }
        acc[r] = a;
    }
#pragma unroll
    for (int r = 0; r < 4; ++r) {
        int i = i0 + r;
        if (i < N) aggP[pk_off(i, d, 8)] = f2h_bits(acc[r]);
    }
}

// ---------------------------------------------------------------------------
// pool_bn [R21]: graph-mean of BN-affine(h16) -> packed f16 (feeds feat gemm).
// BN-affine is linear -> apply AFTER the sum. batch sorted -> contiguous node
// range per graph, fully coalesced reads, ZERO atomics.
// ---------------------------------------------------------------------------
__global__ __launch_bounds__(256)
void pool_bn_kernel(const ushort_t* __restrict__ h16, const float* __restrict__ bnsum,
                    const float* __restrict__ gamma, const float* __restrict__ beta,
                    const int* __restrict__ gstart, const int* __restrict__ gend,
                    ushort_t* __restrict__ poolP, float invN)
{
    int g = blockIdx.x;
    int d = threadIdx.x;
    float mean = bnsum[d] * invN;
    float var = bnsum[D_ + d] * invN - mean * mean;
    float sc = gamma[d] * rsqrtf(fmaxf(var, 0.f) + EPS_);
    float sh = beta[d] - mean * sc;
    int s0 = gstart[g], s1 = gend[g];
    float acc = 0.f;
    int i = s0;
    for (; i + 4 <= s1; i += 4) {
        float a0 = h2f(h16[(size_t)(i + 0) * D_ + d]);
        float a1 = h2f(h16[(size_t)(i + 1) * D_ + d]);
        float a2 = h2f(h16[(size_t)(i + 2) * D_ + d]);
        float a3 = h2f(h16[(size_t)(i + 3) * D_ + d]);
        acc += (a0 + a1) + (a2 + a3);
    }
    for (; i < s1; ++i)
        acc += h2f(h16[(size_t)i * D_ + d]);
    int cnt = s1 - s0;
    float mval = (cnt > 0) ? (sc * acc / (float)cnt + sh) : 0.f;
    poolP[pk_off(g, d, 8)] = f2h_bits(mval);
}

// ---------------------------------------------------------------------------
// weight pack (R16): W fp32 [K][N] -> SINGLE f16 tiles (nb, kb), row = col n
// ---------------------------------------------------------------------------
__global__ __launch_bounds__(256)
void convert_w_pack(const float* __restrict__ W, ushort_t* __restrict__ dh,
                    int N, int nKB)
{
    int kb = blockIdx.x, nb = blockIdx.y;
    int n = threadIdx.x >> 1, half = threadIdx.x & 1;
#pragma unroll
    for (int j = 0; j < 2; ++j) {
        int kq = half * 2 + j;
        size_t o = (size_t)(nb * nKB + kb) * TILE_SH + kq * PLANE_SH + n * 8;
#pragma unroll
        for (int jj = 0; jj < 8; ++jj) {
            float w = W[(size_t)(kb * 32 + kq * 8 + jj) * N + nb * 128 + n];
            dh[o + jj] = f2h_bits(w);
        }
    }
}

// ---------------------------------------------------------------------------
// fused_mlp_kernel [R20]: BOTH layer GEMMs in one kernel. Block = 64 rows x
// 8 waves (512 thr), 2 blocks/CU (LDS 64KB, launch_bounds(512,4)).
//   stage1: T = sp(A @ W1 + b1)  (64x512) -> LDS packed-fragment layout.
//   barrier (the only one)
//   stage2: h = T @ W2 + b2  (64x256) from LDS + W2 (L2-resident).
//   epilogue: h16 row-major f16 + fused bn partial sums (atomics, kq==0).
// T NEVER touches HBM.
// ---------------------------------------------------------------------------
__global__ __launch_bounds__(512, 4)
void fused_mlp_kernel(const ushort_t* __restrict__ APK,
                      const ushort_t* __restrict__ W1P,
                      const ushort_t* __restrict__ W2P,
                      const float* __restrict__ b1,
                      const float* __restrict__ b2,
                      ushort_t* __restrict__ Hout,
                      float* __restrict__ bnsum,
                      int m)
{
    __shared__ ushort_t Tl[32768];   // 64 rows x 512 cols packed f16 = 64 KB

    int rb = blockIdx.x;             // 64-row block
    int tid = threadIdx.x, w = tid >> 6, lane = tid & 63;
    int fr = lane & 15, kq = lane >> 4;

    // ---- stage 1: cols [w*64, w*64+64) ----
    const ushort_t* aT = APK + (size_t)(rb >> 1) * (8 * TILE_SH)
                       + (size_t)kq * PLANE_SH + (size_t)((rb & 1) * 64 + fr) * 8;
    const ushort_t* bT = W1P + (size_t)(w >> 1) * (8 * TILE_SH)
                       + (size_t)kq * PLANE_SH + (size_t)((w & 1) * 64 + fr) * 8;

    f4v acc1[4][4];
#pragma unroll
    for (int i = 0; i < 4; ++i)
#pragma unroll
        for (int j = 0; j < 4; ++j)
            acc1[i][j] = (f4v){0.f, 0.f, 0.f, 0.f};

    for (int kb = 0; kb < 8; ++kb) {
        h8v Af[4], Bf[4];
#pragma unroll
        for (int t = 0; t < 4; ++t) {
            Af[t] = *(const h8v*)(aT + (size_t)kb * TILE_SH + t * 128);
            Bf[t] = *(const h8v*)(bT + (size_t)kb * TILE_SH + t * 128);
        }
        __builtin_amdgcn_s_setprio(1);
#pragma unroll
        for (int rt = 0; rt < 4; ++rt)
#pragma unroll
            for (int ct = 0; ct < 4; ++ct)
                acc1[rt][ct] = __builtin_amdgcn_mfma_f32_16x16x32_f16(
                    Af[rt], Bf[ct], acc1[rt][ct], 0, 0, 0);
        __builtin_amdgcn_s_setprio(0);
    }

    // T -> LDS (packed, unpadded planes). col = w*64 + ct*16 + fr,
    // row = rt*16 + kq*4 + rr. tile = col>>5, plane = (col>>3)&3, j = col&7.
#pragma unroll
    for (int ct = 0; ct < 4; ++ct) {
        float bv = b1[w * 64 + ct * 16 + fr];
        int base = (w * 2 + (ct >> 1)) * 2048
                 + ((( fr >> 3) + ct * 2) & 3) * 512
                 + (fr & 7);
#pragma unroll
        for (int rt = 0; rt < 4; ++rt)
#pragma unroll
            for (int rr = 0; rr < 4; ++rr) {
                int row = rt * 16 + kq * 4 + rr;
                Tl[base + row * 8] = f2h_bits(sp(acc1[rt][ct][rr] + bv));
            }
    }
    __syncthreads();

    // ---- stage 2: cols [w*32, w*32+32) of 256 ----
    const ushort_t* wT = W2P + (size_t)(w >> 2) * (16 * TILE_SH)
                       + (size_t)kq * PLANE_SH + (size_t)((w & 3) * 32 + fr) * 8;

    f4v acc2[4][2];
#pragma unroll
    for (int i = 0; i < 4; ++i)
#pragma unroll
        for (int j = 0; j < 2; ++j)
            acc2[i][j] = (f4v){0.f, 0.f, 0.f, 0.f};

    for (int kb = 0; kb < 16; ++kb) {
        h8v Tf[4], Wf[2];
#pragma unroll
        for (int t = 0; t < 4; ++t)
            Tf[t] = *(const h8v*)(Tl + kb * 2048 + kq * 512 + (fr + t * 16) * 8);
#pragma unroll
        for (int t = 0; t < 2; ++t)
            Wf[t] = *(const h8v*)(wT + (size_t)kb * TILE_SH + t * 128);
        __builtin_amdgcn_s_setprio(1);
#pragma unroll
        for (int rt = 0; rt < 4; ++rt)
#pragma unroll
            for (int ct = 0; ct < 2; ++ct)
                acc2[rt][ct] = __builtin_amdgcn_mfma_f32_16x16x32_f16(
                    Tf[rt], Wf[ct], acc2[rt][ct], 0, 0, 0);
        __builtin_amdgcn_s_setprio(0);
    }

    // ---- epilogue: row-major f16 h + bn partial sums ----
    int gm0 = rb * 64 + kq * 4;
#pragma unroll
    for (int ct = 0; ct < 2; ++ct) {
        int gn = w * 32 + ct * 16 + fr;
        float bv = b2[gn];
        float s = 0.f, ss = 0.f;
#pragma unroll
        for (int rt = 0; rt < 4; ++rt)
#pragma unroll
            for (int rr = 0; rr < 4; ++rr) {
                int gm = gm0 + rt * 16 + rr;
                if (gm < m) {
                    float v = acc2[rt][ct][rr] + bv;
                    Hout[(size_t)gm * D_ + gn] = f2h_bits(v);
                    s += v;
                    ss += v * v;
                }
            }
        s  += __shfl_xor(s, 16);  s  += __shfl_xor(s, 32);
        ss += __shfl_xor(ss, 16); ss += __shfl_xor(ss, 32);
        if (kq == 0) {
            atomicAdd(&bnsum[gn], s);
            atomicAdd(&bnsum[D_ + gn], ss);
        }
    }
}

// ---------------------------------------------------------------------------
// gemm_p16<EPI> [R19 form]  EPI 3: fp32 row-major Cout = A@B + bias (no act)
// ---------------------------------------------------------------------------
template <int EPI>
__global__ __launch_bounds__(256, 3)
void gemm_p16(const ushort_t* __restrict__ APK, const ushort_t* __restrict__ BPK,
              const float* __restrict__ bias,
              ushort_t* __restrict__ Tout, float* __restrict__ Cout,
              float* __restrict__ bnsum, const int* __restrict__ batch,
              int m, int N, int nKB)
{
    const int NB = N >> 7;
    const int mb = (m + 127) >> 7;
    int id = blockIdx.x;
    int grp = id / (8 * NB);
    int rem = id - grp * 8 * NB;
    int nb = rem >> 3;
    int rb = grp * 8 + (rem & 7);
    if (rb >= mb) return;   // uniform early-out (tail row-group)

    int tid = threadIdx.x, wave = tid >> 6, lane = tid & 63;
    int wr = wave >> 1, wc = wave & 1;
    int fr = lane & 15, kq = lane >> 4;

    const ushort_t* aP = APK + (size_t)rb * nKB * TILE_SH
                       + (size_t)kq * PLANE_SH + (size_t)(wr * 64 + fr) * 8;
    const ushort_t* bP = BPK + (size_t)nb * nKB * TILE_SH
                       + (size_t)kq * PLANE_SH + (size_t)(wc * 64 + fr) * 8;

    f4v acc[4][4];
#pragma unroll
    for (int i = 0; i < 4; ++i)
#pragma unroll
        for (int j = 0; j < 4; ++j)
            acc[i][j] = (f4v){0.f, 0.f, 0.f, 0.f};

    h8v Fa[4], Fb[4], Ga[4], Gb[4];

#define LOADF(dA, dB, kbi)                                                   \
    {   const ushort_t* ap_ = aP + (size_t)(kbi) * TILE_SH;                  \
        const ushort_t* bp_ = bP + (size_t)(kbi) * TILE_SH;                  \
        _Pragma("unroll")                                                    \
        for (int t = 0; t < 4; ++t) {                                        \
            dA[t] = *(const h8v*)(ap_ + t * 128);                            \
            dB[t] = *(const h8v*)(bp_ + t * 128);                            \
        } }

#define MFMA16(sA, sB)                                                       \
    {   __builtin_amdgcn_s_setprio(1);                                       \
        _Pragma("unroll")                                                    \
        for (int rt = 0; rt < 4; ++rt)                                       \
            _Pragma("unroll")                                                \
            for (int ct = 0; ct < 4; ++ct)                                   \
                acc[rt][ct] = __builtin_amdgcn_mfma_f32_16x16x32_f16(        \
                    sA[rt], sB[ct], acc[rt][ct], 0, 0, 0);                   \
        __builtin_amdgcn_s_setprio(0); }

    LOADF(Fa, Fb, 0);
    for (int kb = 0; kb < nKB; kb += 2) {
        LOADF(Ga, Gb, kb + 1);
        MFMA16(Fa, Fb);
        if (kb + 2 < nKB) LOADF(Fa, Fb, kb + 2);
        MFMA16(Ga, Gb);
    }
#undef LOADF
#undef MFMA16

    int gm00 = rb * 128 + wr * 64 + kq * 4;
    int gn0  = nb * 128 + wc * 64 + fr;
    int nKBo = N >> 5;
    size_t tileRow = (size_t)(rb * nKBo + nb * 4 + wc * 2) * TILE_SH
                   + (size_t)((wr * 64 + kq * 4) * 8 + (fr & 7));
#pragma unroll
    for (int ct = 0; ct < 4; ++ct) {
        int gn = gn0 + ct * 16;
        float bv = bias[gn];
        float s = 0.f, ss = 0.f;
        size_t cb = tileRow + (size_t)(ct >> 1) * TILE_SH
                  + (size_t)((2 * ct + (fr >> 3)) & 3) * PLANE_SH;
#pragma unroll
        for (int rt = 0; rt < 4; ++rt) {
            if (EPI == 2) {
                int bp = -1; float run = 0.f;
#pragma unroll
                for (int rr = 0; rr < 4; ++rr) {
                    int gm = gm00 + rt * 16 + rr;
                    if (gm >= m) continue;
                    float v = acc[rt][ct][rr] + bv;
                    int bg = batch[gm];
                    if (bg == bp) { run += v; }
                    else {
                        if (bp >= 0) atomicAdd(&Cout[(size_t)bp * N + gn], run);
                        bp = bg; run = v;
                    }
                }
                if (bp >= 0) atomicAdd(&Cout[(size_t)bp * N + gn], run);
            } else {
#pragma unroll
                for (int rr = 0; rr < 4; ++rr) {
                    int gm = gm00 + rt * 16 + rr;
                    if (gm >= m) continue;
                    float v = acc[rt][ct][rr] + bv;
                    if (EPI == 0) {
                        Tout[cb + (rt * 16 + rr) * 8] = f2h_bits(sp(v));
                    } else if (EPI == 1) {
                        Tout[(size_t)gm * N + gn] = f2h_bits(v);
                        s += v;
                        ss += v * v;
                    } else {  // EPI == 3: fp32 row-major, no activation
                        Cout[(size_t)gm * N + gn] = v;
                    }
                }
            }
        }
        if (EPI == 1) {
            s  += __shfl_xor(s, 16);  s  += __shfl_xor(s, 32);
            ss += __shfl_xor(ss, 16); ss += __shfl_xor(ss, 32);
            if (kq == 0) {
                atomicAdd(&bnsum[gn], s);
                atomicAdd(&bnsum[D_ + gn], ss);
            }
        }
    }
}

// ---------------------------------------------------------------------------
// fp32 GEMM for the small head: C = softplus(A @ W + bias)
// ---------------------------------------------------------------------------
#define BM 64
#define BN 64
#define BK 16

__global__ __launch_bounds__(256)
void gemm_head(const float* __restrict__ A, const float* __restrict__ W,
               const float* __restrict__ bias, float* __restrict__ C,
               int M, int N, int K)
{
    __shared__ float As[BK][BM + 4];
    __shared__ float Ws[BK][BN + 4];

    int tid = threadIdx.x;
    int bm = blockIdx.y * BM;
    int bn = blockIdx.x * BN;
    int tx = tid & 15;
    int ty = tid >> 4;

    float acc[4][4] = {};

    int a_m = tid >> 2;
    int a_k = (tid & 3) * 4;
    int w_k = tid >> 4;
    int w_n = (tid & 15) * 4;

    for (int k0 = 0; k0 < K; k0 += BK) {
        int gm = bm + a_m;
        float4 av = make_float4(0.f, 0.f, 0.f, 0.f);
        if (gm < M)
            av = *(const float4*)(A + (size_t)gm * K + k0 + a_k);
        As[a_k + 0][a_m] = av.x;
        As[a_k + 1][a_m] = av.y;
        As[a_k + 2][a_m] = av.z;
        As[a_k + 3][a_m] = av.w;

        float4 wv = *(const float4*)(W + (size_t)(k0 + w_k) * N + bn + w_n);
        *(float4*)&Ws[w_k][w_n] = wv;

        __syncthreads();

#pragma unroll
        for (int k = 0; k < BK; ++k) {
            float4 a4 = *(const float4*)&As[k][ty * 4];
            float4 b4 = *(const float4*)&Ws[k][tx * 4];
            float a[4] = {a4.x, a4.y, a4.z, a4.w};
            float b[4] = {b4.x, b4.y, b4.z, b4.w};
#pragma unroll
            for (int i = 0; i < 4; ++i)
#pragma unroll
                for (int j = 0; j < 4; ++j)
                    acc[i][j] += a[i] * b[j];
        }
        __syncthreads();
    }

#pragma unroll
    for (int i = 0; i < 4; ++i) {
        int gm = bm + ty * 4 + i;
        if (gm >= M) continue;
#pragma unroll
        for (int j = 0; j < 4; ++j) {
            int gn = bn + tx * 4 + j;
            C[(size_t)gm * N + gn] = sp(acc[i][j] + bias[gn]);
        }
    }
}

__global__ __launch_bounds__(256)
void head2_kernel(const float* __restrict__ hid, const float* __restrict__ w2,
                  const float* __restrict__ b2, float* __restrict__ out, int G)
{
    __shared__ float red[256];
    int g = blockIdx.x;
    int t = threadIdx.x;
    float v = hid[(size_t)g * 256 + t] * w2[t];
    red[t] = v;
    __syncthreads();
    for (int s = 128; s > 0; s >>= 1) {
        if (t < s) red[t] += red[t + s];
        __syncthreads();
    }
    if (t == 0) out[g] = red[0] + b2[0];
}

// ---------------------------------------------------------------------------
extern "C" void kernel_launch(void* const* d_in, const int* in_sizes, int n_in,
                              void* d_out, int out_size, void* d_ws, size_t ws_size,
                              hipStream_t stream)
{
    const int N = in_sizes[0];
    const int E = in_sizes[3];
    const int G = out_size;

    const int*   atomics  = (const int*)d_in[0];
    const float* pos      = (const float*)d_in[1];
    const int*   eidx     = (const int*)d_in[2];
    const int*   eattr    = (const int*)d_in[3];
    const int*   batch    = (const int*)d_in[4];
    const float* x_emb1   = (const float*)d_in[5];
    const float* x_emb2_w = (const float*)d_in[6];
    const float* x_emb2_b = (const float*)d_in[7];
    const float* edge_emb = (const float*)d_in[8];
    const float* mlp_w1   = (const float*)d_in[9];
    const float* mlp_b1   = (const float*)d_in[10];
    const float* mlp_w2   = (const float*)d_in[11];
    const float* mlp_b2   = (const float*)d_in[12];
    const float* bn_g     = (const float*)d_in[13];
    const float* bn_b     = (const float*)d_in[14];
    const float* feat_w   = (const float*)d_in[15];
    const float* feat_b   = (const float*)d_in[16];
    const float* head_w1  = (const float*)d_in[17];
    const float* head_b1  = (const float*)d_in[18];
    const float* head_w2  = (const float*)d_in[19];
    const float* head_b2  = (const float*)d_in[20];
    float* out = (float*)d_out;

    const int* src = eidx;
    const int* dst = eidx + E;

    char* ws = (char*)d_ws;
    size_t off = 0;
    auto carve = [&](size_t bytes) {
        void* p = ws + off;
        off += (bytes + 255) & ~(size_t)255;
        return p;
    };

    const int nRB = (N + 127) / 128;           // 128-row tiles
    const int nGB = (G + 127) / 128;           // 128-row tiles of pooled

    // ---- fixed carve (~170 MB) ----
    ushort_t* h16  = (ushort_t*)carve((size_t)N * D_ * 2);             // 51.2 MB
    ushort_t* hact = (ushort_t*)carve((size_t)N * D_ * 2);             // 51.2 MB
    ushort_t* aggP = (ushort_t*)carve((size_t)nRB * 8 * TILE_SH * 2);  // 52.9 MB
    const size_t WTILES = 32 * TILE_SH;
    ushort_t* w1P = (ushort_t*)carve((size_t)L_ * WTILES * 2);
    ushort_t* w2P = (ushort_t*)carve((size_t)L_ * WTILES * 2);
    ushort_t* fP  = (ushort_t*)carve(WTILES * 2);
    float* bnsum  = (float*)carve(2 * D_ * 4);
    float* gfeat  = (float*)carve((size_t)G * FD_ * 4);                // 8.2 MB
    float* hid    = (float*)carve((size_t)G * (FD_ / 2) * 4);
    ushort_t* poolP = (ushort_t*)carve((size_t)nGB * 8 * TILE_SH * 2); // 2.2 MB
    int* gstart  = (int*)carve((size_t)G * 4);
    int* gend    = (int*)carve((size_t)G * 4);
    // CSR buffers (~5 MB)
    int* cnt_i   = (int*)carve((size_t)N * 4);
    int* start_i = (int*)carve((size_t)N * 4);
    int* cursor  = (int*)carve((size_t)N * 4);
    int* total   = (int*)carve(4);
    uint32_t* elist = (uint32_t*)carve((size_t)E * 4);

    const float invN = 1.f / (float)N;

    // ---- CSR build (once per launch, reused all 5 layers) ----
    hipMemsetAsync(cnt_i, 0, (size_t)N * 4, stream);
    hipMemsetAsync(total, 0, 4, stream);
    hipMemsetAsync(gstart, 0, (size_t)G * 4, stream);
    hipMemsetAsync(gend, 0, (size_t)G * 4, stream);
    hist_kernel<<<(E + 255) / 256, 256, 0, stream>>>(dst, cnt_i, E);
    alloc_kernel<<<(N + 255) / 256, 256, 0, stream>>>(cnt_i, start_i, cursor, total, N);
    fill_kernel<<<(E + 255) / 256, 256, 0, stream>>>(src, dst, eattr, cursor, elist, E);
    range_kernel<<<(N + 255) / 256, 256, 0, stream>>>(batch, gstart, gend, N);

    // ---- one-time weight packing (single f16) ----
    for (int l = 0; l < L_; ++l) {
        convert_w_pack<<<dim3(8, 4), 256, 0, stream>>>(
            mlp_w1 + (size_t)l * D_ * FD_, w1P + (size_t)l * WTILES, FD_, 8);
        convert_w_pack<<<dim3(16, 2), 256, 0, stream>>>(
            mlp_w2 + (size_t)l * FD_ * D_, w2P + (size_t)l * WTILES, D_, 16);
    }
    convert_w_pack<<<dim3(8, 4), 256, 0, stream>>>(feat_w, fP, FD_, 8);

    init_h_kernel<<<N, 256, 0, stream>>>(atomics, pos, x_emb1, x_emb2_w, x_emb2_b, h16, N);

    const long long total8 = (long long)N * D_ / 8;
    const int ACTB = (int)((total8 + 255) / 256);
    const int GB4 = (N + 3) / 4;
    const int FB  = (N + 63) / 64;             // fused 64-row blocks

    for (int l = 0; l < L_; ++l) {
        const float* ee_l = edge_emb + (size_t)l * 2 * D_;
        const ushort_t* gsrc = h16;
        if (l > 0) {
            act16_kernel<<<ACTB, 256, 0, stream>>>(h16, hact, bnsum,
                bn_g + (size_t)(l - 1) * D_, bn_b + (size_t)(l - 1) * D_, total8, invN);
            gsrc = hact;
        }
        gather_pack4_kernel<<<GB4, 256, 0, stream>>>(gsrc, elist, start_i, cnt_i,
                                                     ee_l, aggP, N);

        hipMemsetAsync(bnsum, 0, 2 * D_ * 4, stream);
        fused_mlp_kernel<<<FB, 512, 0, stream>>>(
            aggP, w1P + (size_t)l * WTILES, w2P + (size_t)l * WTILES,
            mlp_b1 + (size_t)l * FD_, mlp_b2 + (size_t)l * D_,
            h16, bnsum, N);
    }

    // ---- pool-first feat path: gfeat = mean_g(BN(h16)) @ feat_w + feat_b ----
    pool_bn_kernel<<<G, 256, 0, stream>>>(h16, bnsum, bn_g + (size_t)(L_ - 1) * D_,
                                          bn_b + (size_t)(L_ - 1) * D_,
                                          gstart, gend, poolP, invN);
    auto swgrid = [](int mb, int NBc) { return ((mb + 7) / 8) * 8 * NBc; };
    gemm_p16<3><<<swgrid(nGB, 4), 256, 0, stream>>>(
        poolP, fP, feat_b, nullptr, gfeat, nullptr, nullptr, G, FD_, 8);

    // ---- head ----
    gemm_head<<<dim3((FD_ / 2) / BN, (G + BM - 1) / BM), 256, 0, stream>>>(
        gfeat, head_w1, head_b1, hid, G, FD_ / 2, FD_);
    head2_kernel<<<G, 256, 0, stream>>>(hid, head_w2, head_b2, out, G);
}